// Round 3
// baseline (252.003 us; speedup 1.0000x reference)
//
#include <hip/hip_runtime.h>
#include <math.h>

// DecoderLayer: B=4,N=1,S=256,D=128,H=128,DFF=512, fp32 end-to-end.
// Round-12: 3 dispatches -> 1 mega-kernel (+1 tiny memset graph node).
// Evidence: R9(5disp)=182, R10(5disp,2xocc)=172, R11(3disp)=174 -- structure-
// invariant ~175us while all our kernels are <40us each (top-5 = harness
// fills). Sum of kernels <= 120us < 174us => >=55us is graph-node gaps /
// launch overhead. This round removes ALL internal boundaries.
// Structural key: attn2 depends on attn1 ONLY via block-local data (qa2/qb2/
// out1 are produced and consumed by the same 4-row block) -> exactly ONE
// device-wide barrier needed (after proj). qa2/qb2/out1 now live in LDS only.
// Barrier: device-scope atomic counter + acquire spin (G16). Grid=256 blocks,
// 512thr, 76KB LDS -> capacity >= 2 blocks/CU * 256 CU = 512 >= 256 grid ->
// all blocks co-resident -> spin is deadlock-free. Counter zeroed each graph
// replay by hipMemsetAsync node (poison-proof).
// b2 dropped (softmax shift invariance). RES_RATIO=1 -> plain residual add.

#define LN_EPS 1e-6f
#define NEGV  (-1e9f)

constexpr int B = 4, S = 256, D = 128, H = 128, DFF = 512;
constexpr int R = B * S;   // 1024 rows (N=1)
constexpr int SP = 132;    // streamed k-tile LDS row stride (floats)
constexpr unsigned int NBLK = 256;

struct P {
    const float *x, *enc, *com_mask, *dec_mask;
    const float *W1q, *W1k, *b1, *W2;
    const float *Ww1, *bw1, *Wd1, *bd1;
    const float *Ww2, *bw2, *Wd2, *bd2;
    const float *Wf1, *bf1, *Wf2, *bf2;
    const float *ln1g, *ln1b, *ln2g, *ln2b, *ln3g, *ln3b;
    float *out;
    unsigned int *ctr;
    float *xw, *qa, *kb, *kv2w, *kb2, *ka2;
};

// ---- scoring: 8 fma/fmax pairs (two relu-dot terms, 4 h-components) ----
#define SC8(ACC, O1, X1, O2, X2)                                               \
    ACC = fmaf(fmaxf((O1).x + (X1).x, 0.f), w.x, ACC);                         \
    ACC = fmaf(fmaxf((O1).y + (X1).y, 0.f), w.y, ACC);                         \
    ACC = fmaf(fmaxf((O1).z + (X1).z, 0.f), w.z, ACC);                         \
    ACC = fmaf(fmaxf((O1).w + (X1).w, 0.f), w.w, ACC);                         \
    ACC = fmaf(fmaxf((O2).x + (X2).x, 0.f), w.x, ACC);                         \
    ACC = fmaf(fmaxf((O2).y + (X2).y, 0.f), w.y, ACC);                         \
    ACC = fmaf(fmaxf((O2).z + (X2).z, 0.f), w.z, ACC);                         \
    ACC = fmaf(fmaxf((O2).w + (X2).w, 0.f), w.w, ACC);

// ====== fused attn stage: scoring + softmax + AV + outproj + LN + tail ======
// smem (floats): s8 [0,1024) | rowS [1024,1536) | stg1 [1536,9984) |
//   stg2 [9984,18432) | qa2L [18432,18944) | qb2L [18944,19456).
// Post-scoring aliases in stg region: avp@1536(2048) aoS@3584(512)
//   pp@4096(2048) qpp@6144(2048) q2wS@8192(512) qp2@8704(2048)
//   | FFN: hidP@1536(8192) part@9984(8192).
template<bool FIRST>
__device__ __forceinline__ void attn_stage(const P& p, float* smem,
                                           int tid, int r0, int bS)
{
    float* s8   = smem;          // [4][256] scores -> probs
    float* rowS = smem + 1024;   // [4][128] LN output (out1 survives here)
    float* qa2L = smem + 18432;  // [4][128]
    float* qb2L = smem + 18944;  // [4][128]

    const float* S1g  = FIRST ? p.kb : p.kb2;   // streamed term1 array
    const float* S2g  = FIRST ? p.qa : p.ka2;   // streamed term2 array
    const float* mask = FIRST ? p.com_mask : p.dec_mask;
    const float* V    = FIRST ? p.xw : p.kv2w;
    const float* Wd   = FIRST ? p.Wd1 : p.Wd2;
    const float* bd   = FIRST ? p.bd1 : p.bd2;
    const float* lg   = FIRST ? p.ln1g : p.ln2g;
    const float* lb   = FIRST ? p.ln1b : p.ln2b;

    // ---------------- scoring ----------------
    // s[r,k] = sum_h relu(O1[r,h]+S1[k,h])*W2[h] + relu(O2[r,h]+S2[k,h])*W2[h]
    // thread: hh = tid&7 (h-split, h = hh*4 + 32j), unit = tid>>3:
    //   kk = unit&31 (k-pair {kk, kk+32} within 64-row tile), rg = unit>>5.
    {
        float* stg1 = smem + 1536;   // [64][SP]
        float* stg2 = smem + 9984;   // [64][SP]
        const int hh = tid & 7, unit = tid >> 3, kk = unit & 31, rg = unit >> 5;
        const int rA = r0 + 2 * rg, rB = rA + 1;

        float4 o1A[4], o1B[4], o2A[4], o2B[4], w2r[4];
        #pragma unroll
        for (int j = 0; j < 4; ++j) {
            const int h = hh * 4 + 32 * j;
            if (FIRST) {
                o1A[j] = *(const float4*)(p.qa + (size_t)rA * H + h);
                o1B[j] = *(const float4*)(p.qa + (size_t)rB * H + h);
                o2A[j] = *(const float4*)(p.kb + (size_t)rA * H + h);
                o2B[j] = *(const float4*)(p.kb + (size_t)rB * H + h);
            } else {
                o1A[j] = *(const float4*)(qa2L + (2 * rg)     * H + h);
                o1B[j] = *(const float4*)(qa2L + (2 * rg + 1) * H + h);
                o2A[j] = *(const float4*)(qb2L + (2 * rg)     * H + h);
                o2B[j] = *(const float4*)(qb2L + (2 * rg + 1) * H + h);
            }
            w2r[j] = *(const float4*)(p.W2 + h);
        }
        __syncthreads();   // qa2L stable / smem reuse safe

        for (int kt = 0; kt < 4; ++kt) {
            // stage 64 rows of S1,S2 (coalesced; 8 float4 per thread)
            #pragma unroll
            for (int t = 0; t < 8; ++t) {
                const int fi = tid + t * 512;
                const int arr = fi >> 11, row = (fi >> 5) & 63, cf = (fi & 31) * 4;
                const float* gp = (arr ? S2g : S1g) + (size_t)(bS + kt * 64 + row) * H + cf;
                float* dp = (arr ? stg2 : stg1) + row * SP + cf;
                *(float4*)dp = *(const float4*)gp;
            }
            __syncthreads();

            const float* s1a = stg1 + kk * SP;
            const float* s1b = stg1 + (kk + 32) * SP;
            const float* s2a = stg2 + kk * SP;
            const float* s2b = stg2 + (kk + 32) * SP;
            float aAa = 0.f, aAb = 0.f, aBa = 0.f, aBb = 0.f;
            #pragma unroll
            for (int j = 0; j < 4; ++j) {
                const int h = hh * 4 + 32 * j;
                const float4 w = w2r[j];
                const float4 x1a = *(const float4*)(s1a + h);
                const float4 x1b = *(const float4*)(s1b + h);
                const float4 x2a = *(const float4*)(s2a + h);
                const float4 x2b = *(const float4*)(s2b + h);
                SC8(aAa, o1A[j], x1a, o2A[j], x2a)
                SC8(aAb, o1A[j], x1b, o2A[j], x2b)
                SC8(aBa, o1B[j], x1a, o2B[j], x2a)
                SC8(aBb, o1B[j], x1b, o2B[j], x2b)
            }
            // h-reduce across the 8 hh lanes of this unit (width-8 shuffle)
            #pragma unroll
            for (int o = 1; o < 8; o <<= 1) {
                aAa += __shfl_xor(aAa, o, 8);
                aAb += __shfl_xor(aAb, o, 8);
                aBa += __shfl_xor(aBa, o, 8);
                aBb += __shfl_xor(aBb, o, 8);
            }
            if (hh == 0) {
                const int kb0 = kt * 64;
                s8[(2 * rg)     * 256 + kb0 + kk]      = aAa;
                s8[(2 * rg)     * 256 + kb0 + kk + 32] = aAb;
                s8[(2 * rg + 1) * 256 + kb0 + kk]      = aBa;
                s8[(2 * rg + 1) * 256 + kb0 + kk + 32] = aBb;
            }
            __syncthreads();
        }
    }

    // ---- mask add ----
    for (int i = tid; i < 1024; i += 512) {
        const int r = i >> 8, k = i & 255;
        s8[i] += mask[(size_t)(r0 + r) * S + k] * NEGV;
    }
    __syncthreads();

    // ---- softmax: waves 0-3 own rows 0-3; 64-lane shuffles ----
    {
        const int g = tid >> 6, c = tid & 63;
        if (g < 4) {
            float* rowp = s8 + g * 256;
            float m = -INFINITY;
            #pragma unroll
            for (int k = c; k < 256; k += 64) m = fmaxf(m, rowp[k]);
            for (int o = 32; o; o >>= 1) m = fmaxf(m, __shfl_xor(m, o, 64));
            float s = 0.f;
            #pragma unroll
            for (int k = c; k < 256; k += 64) { const float e = __expf(rowp[k] - m); rowp[k] = e; s += e; }
            for (int o = 32; o; o >>= 1) s += __shfl_xor(s, o, 64);
            const float rinv = 1.f / s;
            #pragma unroll
            for (int k = c; k < 256; k += 64) rowp[k] *= rinv;
        }
    }
    __syncthreads();

    float* avp = smem + 1536;   // [4][4][128] AV k-split partials
    float* aoS = smem + 3584;   // [4][128]
    float* pp  = smem + 4096;   // [4][4][128] outproj partials

    // ---- AV, k-split x4: row r, quarter kq ----
    {
        const int r = tid >> 7, t = tid & 127, kq = t >> 5, c4 = t & 31;
        const float4* V4 = (const float4*)(V + (size_t)bS * D);
        const float* sp = s8 + r * 256 + kq * 64;
        float4 acc = make_float4(0.f, 0.f, 0.f, 0.f);
        #pragma unroll 8
        for (int k = 0; k < 64; ++k) {
            const float a = sp[k];
            const float4 v = V4[(kq * 64 + k) * 32 + c4];
            acc.x = fmaf(a, v.x, acc.x); acc.y = fmaf(a, v.y, acc.y);
            acc.z = fmaf(a, v.z, acc.z); acc.w = fmaf(a, v.w, acc.w);
        }
        ((float4*)avp)[(r * 4 + kq) * 32 + c4] = acc;
    }
    __syncthreads();
    if (tid < 128) {
        const int r = tid >> 5, c4 = tid & 31;
        float4 s0 = ((const float4*)avp)[(r * 4 + 0) * 32 + c4];
        const float4 s1 = ((const float4*)avp)[(r * 4 + 1) * 32 + c4];
        const float4 s2 = ((const float4*)avp)[(r * 4 + 2) * 32 + c4];
        const float4 s3 = ((const float4*)avp)[(r * 4 + 3) * 32 + c4];
        s0.x += s1.x + s2.x + s3.x; s0.y += s1.y + s2.y + s3.y;
        s0.z += s1.z + s2.z + s3.z; s0.w += s1.w + s2.w + s3.w;
        ((float4*)aoS)[r * 32 + c4] = s0;
    }
    __syncthreads();

    // ---- outproj, k-split x4 ----
    {
        const int kq = tid >> 7, unit = tid & 127, r = unit >> 5, c4 = unit & 31;
        const float4* W4 = (const float4*)Wd;
        const float* ap = aoS + r * 128 + kq * 32;
        float4 acc = make_float4(0.f, 0.f, 0.f, 0.f);
        #pragma unroll 8
        for (int k = 0; k < 32; ++k) {
            const float a = ap[k];
            const float4 w = W4[(kq * 32 + k) * 32 + c4];
            acc.x = fmaf(a, w.x, acc.x); acc.y = fmaf(a, w.y, acc.y);
            acc.z = fmaf(a, w.z, acc.z); acc.w = fmaf(a, w.w, acc.w);
        }
        ((float4*)pp)[kq * 128 + unit] = acc;
    }
    __syncthreads();

    // ---- combine + bias + residual + LN -> rowS ----
    if (tid < 128) {
        const int r = tid >> 5, c4 = tid & 31;
        const float4 p0 = ((const float4*)pp)[tid];
        const float4 p1 = ((const float4*)pp)[128 + tid];
        const float4 p2 = ((const float4*)pp)[256 + tid];
        const float4 p3 = ((const float4*)pp)[384 + tid];
        const float4 bv0 = ((const float4*)bd)[c4];
        float4 r4;
        if (FIRST) r4 = ((const float4*)(p.x + (size_t)(r0 + r) * 128))[c4];
        else       r4 = ((const float4*)rowS)[r * 32 + c4];
        const float x0 = p0.x + p1.x + p2.x + p3.x + bv0.x + r4.x;
        const float x1 = p0.y + p1.y + p2.y + p3.y + bv0.y + r4.y;
        const float x2 = p0.z + p1.z + p2.z + p3.z + bv0.z + r4.z;
        const float x3 = p0.w + p1.w + p2.w + p3.w + bv0.w + r4.w;
        float s  = x0 + x1 + x2 + x3;
        float s2 = x0 * x0 + x1 * x1 + x2 * x2 + x3 * x3;
        for (int o = 16; o; o >>= 1) { s += __shfl_xor(s, o, 32); s2 += __shfl_xor(s2, o, 32); }
        const float m = s * (1.f / 128), var = s2 * (1.f / 128) - m * m;
        const float rs = rsqrtf(var + LN_EPS);
        const float4 gv = ((const float4*)lg)[c4], bv = ((const float4*)lb)[c4];
        float4 o4;
        o4.x = (x0 - m) * rs * gv.x + bv.x; o4.y = (x1 - m) * rs * gv.y + bv.y;
        o4.z = (x2 - m) * rs * gv.z + bv.z; o4.w = (x3 - m) * rs * gv.w + bv.w;
        ((float4*)rowS)[r * 32 + c4] = o4;
    }
    __syncthreads();

    if (FIRST) {
        // ---- qproj: q2w = LN1out@Ww2+bw2; qa2/qb2 = q2w@{W1q,W1k}+b1 -> LDS
        float* qpp  = smem + 6144;  // [4][4][32] f4 partials (2048 floats)
        float* q2wS = smem + 8192;  // [4][128]
        float* qp2  = smem + 8704;  // [2][2][128] f4 partials (2048 floats)
        {   // q2w partials, k-split x4
            const int kq = tid >> 7, unit = tid & 127, r = unit >> 5, c4 = unit & 31;
            const float4* W4 = (const float4*)p.Ww2;
            const float* ap = rowS + r * 128 + kq * 32;
            float4 acc = make_float4(0.f, 0.f, 0.f, 0.f);
            #pragma unroll 8
            for (int k = 0; k < 32; ++k) {
                const float a = ap[k];
                const float4 w = W4[(kq * 32 + k) * 32 + c4];
                acc.x = fmaf(a, w.x, acc.x); acc.y = fmaf(a, w.y, acc.y);
                acc.z = fmaf(a, w.z, acc.z); acc.w = fmaf(a, w.w, acc.w);
            }
            ((float4*)qpp)[kq * 128 + unit] = acc;
        }
        __syncthreads();
        if (tid < 128) {
            const int c4 = tid & 31;
            const float4 p0 = ((const float4*)qpp)[tid];
            const float4 p1 = ((const float4*)qpp)[128 + tid];
            const float4 p2 = ((const float4*)qpp)[256 + tid];
            const float4 p3 = ((const float4*)qpp)[384 + tid];
            const float4 bw = ((const float4*)p.bw2)[c4];
            ((float4*)q2wS)[tid] = make_float4(p0.x + p1.x + p2.x + p3.x + bw.x,
                                               p0.y + p1.y + p2.y + p3.y + bw.y,
                                               p0.z + p1.z + p2.z + p3.z + bw.z,
                                               p0.w + p1.w + p2.w + p3.w + bw.w);
        }
        __syncthreads();
        {   // qa2 = q2w@W1q + b1 ; qb2 = q2w@W1k + b1 ; k-split x2
            const int which = tid >> 8, sub = tid & 255;
            const int kh = sub >> 7, unit2 = sub & 127;
            const float4* W4 = (const float4*)(which ? p.W1k : p.W1q);
            const int r = unit2 >> 5;
            const float* ap = q2wS + r * 128 + kh * 64;
            float4 acc = make_float4(0.f, 0.f, 0.f, 0.f);
            #pragma unroll 8
            for (int k = 0; k < 64; ++k) {
                const float a = ap[k];
                const float4 w = W4[(kh * 64 + k) * 32 + (unit2 & 31)];
                acc.x = fmaf(a, w.x, acc.x); acc.y = fmaf(a, w.y, acc.y);
                acc.z = fmaf(a, w.z, acc.z); acc.w = fmaf(a, w.w, acc.w);
            }
            ((float4*)qp2)[(which * 2 + kh) * 128 + unit2] = acc;
        }
        __syncthreads();
        if (tid < 256) {   // reduce 2 k-halves + b1 -> qa2L/qb2L (LDS only)
            const int which = tid >> 7, unit2 = tid & 127;
            const int c4 = unit2 & 31;
            const float4 p0 = ((const float4*)qp2)[(which * 2 + 0) * 128 + unit2];
            const float4 p1 = ((const float4*)qp2)[(which * 2 + 1) * 128 + unit2];
            const float4 b1v = ((const float4*)p.b1)[c4];
            float* oq = which ? qb2L : qa2L;
            ((float4*)oq)[unit2] =
                make_float4(p0.x + p1.x + b1v.x, p0.y + p1.y + b1v.y,
                            p0.z + p1.z + b1v.z, p0.w + p1.w + b1v.w);
        }
        __syncthreads();
    } else {
        // ---- FFN + LN3 -> out ----
        float* hidP = smem + 1536;  // [4 kh][4 r][512] partials; [0,2048) -> hidden
        float* part = smem + 9984;  // [16 kg][4 r][128]
        {   // ffn1: float4-col c of 128 (DFF/4), k-quarter kh; 4-row reg accs
            const int c = tid & 127, kh = tid >> 7;
            const float4* Wf1_4 = (const float4*)p.Wf1;
            float4 a0 = make_float4(0.f,0.f,0.f,0.f), a1 = a0, a2 = a0, a3 = a0;
            const int kbase = kh * 32;
            #pragma unroll 8
            for (int k = 0; k < 32; ++k) {
                const int kk = kbase + k;
                const float4 w = Wf1_4[kk * 128 + c];
                const float s0 = rowS[kk],       s1 = rowS[128 + kk];
                const float s2 = rowS[256 + kk], s3 = rowS[384 + kk];
                a0.x=fmaf(s0,w.x,a0.x); a0.y=fmaf(s0,w.y,a0.y); a0.z=fmaf(s0,w.z,a0.z); a0.w=fmaf(s0,w.w,a0.w);
                a1.x=fmaf(s1,w.x,a1.x); a1.y=fmaf(s1,w.y,a1.y); a1.z=fmaf(s1,w.z,a1.z); a1.w=fmaf(s1,w.w,a1.w);
                a2.x=fmaf(s2,w.x,a2.x); a2.y=fmaf(s2,w.y,a2.y); a2.z=fmaf(s2,w.z,a2.z); a2.w=fmaf(s2,w.w,a2.w);
                a3.x=fmaf(s3,w.x,a3.x); a3.y=fmaf(s3,w.y,a3.y); a3.z=fmaf(s3,w.z,a3.z); a3.w=fmaf(s3,w.w,a3.w);
            }
            float4* h4 = (float4*)hidP;
            const int base = kh * 512;
            h4[base + 0*128 + c] = a0; h4[base + 1*128 + c] = a1;
            h4[base + 2*128 + c] = a2; h4[base + 3*128 + c] = a3;
        }
        __syncthreads();
        for (int i = tid; i < 2048; i += 512) {   // reduce 4 k-quarters + relu
            hidP[i] = fmaxf(hidP[i] + hidP[2048 + i] + hidP[4096 + i] + hidP[6144 + i]
                            + p.bf1[i & 511], 0.f);
        }
        __syncthreads();
        {   // ffn2: c4f of 32, k-group kg (16 x 32); 4-row reg accs
            const int c4f = tid & 31, kg = tid >> 5;
            const float4* Wf2_4 = (const float4*)p.Wf2;
            float4 a0 = make_float4(0.f,0.f,0.f,0.f), a1 = a0, a2 = a0, a3 = a0;
            const int kbase = kg * 32;
            const float* h0 = hidP + 0 * 512 + kbase;
            const float* h1 = hidP + 1 * 512 + kbase;
            const float* h2 = hidP + 2 * 512 + kbase;
            const float* h3 = hidP + 3 * 512 + kbase;
            #pragma unroll 8
            for (int k = 0; k < 32; ++k) {
                const float4 w = Wf2_4[(kbase + k) * 32 + c4f];
                const float s0 = h0[k], s1 = h1[k], s2 = h2[k], s3 = h3[k];
                a0.x=fmaf(s0,w.x,a0.x); a0.y=fmaf(s0,w.y,a0.y); a0.z=fmaf(s0,w.z,a0.z); a0.w=fmaf(s0,w.w,a0.w);
                a1.x=fmaf(s1,w.x,a1.x); a1.y=fmaf(s1,w.y,a1.y); a1.z=fmaf(s1,w.z,a1.z); a1.w=fmaf(s1,w.w,a1.w);
                a2.x=fmaf(s2,w.x,a2.x); a2.y=fmaf(s2,w.y,a2.y); a2.z=fmaf(s2,w.z,a2.z); a2.w=fmaf(s2,w.w,a2.w);
                a3.x=fmaf(s3,w.x,a3.x); a3.y=fmaf(s3,w.y,a3.y); a3.z=fmaf(s3,w.z,a3.z); a3.w=fmaf(s3,w.w,a3.w);
            }
            float4* p4 = (float4*)part;
            p4[kg * 128 + 0 * 32 + c4f] = a0; p4[kg * 128 + 1 * 32 + c4f] = a1;
            p4[kg * 128 + 2 * 32 + c4f] = a2; p4[kg * 128 + 3 * 32 + c4f] = a3;
        }
        __syncthreads();
        if (tid < 128) {  // reduce 16 k-partials + bias + residual + LN3 -> out
            const int r = tid >> 5, c4 = tid & 31;
            const float4* p4 = (const float4*)part;
            float4 sum = ((const float4*)p.bf2)[c4];
            #pragma unroll
            for (int kg = 0; kg < 16; ++kg) {
                const float4 v = p4[kg * 128 + r * 32 + c4];
                sum.x += v.x; sum.y += v.y; sum.z += v.z; sum.w += v.w;
            }
            const float4 r4 = ((const float4*)rowS)[r * 32 + c4];
            const float x0 = sum.x + r4.x, x1 = sum.y + r4.y;
            const float x2 = sum.z + r4.z, x3 = sum.w + r4.w;
            float s  = x0 + x1 + x2 + x3;
            float s2 = x0 * x0 + x1 * x1 + x2 * x2 + x3 * x3;
            for (int o = 16; o; o >>= 1) { s += __shfl_xor(s, o, 32); s2 += __shfl_xor(s2, o, 32); }
            const float m = s * (1.f / 128), var = s2 * (1.f / 128) - m * m;
            const float rs = rsqrtf(var + LN_EPS);
            const float4 gv = ((const float4*)p.ln3g)[c4], bv = ((const float4*)p.ln3b)[c4];
            float4 o4;
            o4.x = (x0 - m) * rs * gv.x + bv.x; o4.y = (x1 - m) * rs * gv.y + bv.y;
            o4.z = (x2 - m) * rs * gv.z + bv.z; o4.w = (x3 - m) * rs * gv.w + bv.w;
            ((float4*)p.out)[(size_t)(r0 + r) * 32 + c4] = o4;
        }
    }
}

// ============================ mega kernel ============================
__global__ __launch_bounds__(512) void mega_kernel(P p)
{
    __shared__ __align__(16) float smem[19456];
    const int tid = threadIdx.x, bid = blockIdx.x;

    // ---------- stage A: chained projections (8 rows per block) ----------
    {
        const int g = bid >> 7;            // 0: x-side, 1: enc-side
        const int r0p = (bid & 127) * 8;
        float* Ash = smem + 1536;          // [8][128]
        float* Pw  = smem + 2560;          // [8][128]
        float* Pp  = smem + 3584;          // [2][8][128] k-split partials

        const float* A    = g ? p.enc  : p.x;
        const float* Wp   = g ? p.Ww2  : p.Ww1;
        const float* bp   = g ? p.bw2  : p.bw1;
        float*       o_w  = g ? p.kv2w : p.xw;
        const float* Wsec = g ? p.W1k  : p.W1q;  // kb2 | qa
        const float* bsec = g ? nullptr: p.b1;
        float*       o_s  = g ? p.kb2  : p.qa;
        const float* Wthr = g ? p.W1q  : p.W1k;  // ka2 | kb
        float*       o_t  = g ? p.ka2  : p.kb;

        if (tid < 256)
            ((float4*)Ash)[tid] = ((const float4*)(A + (size_t)r0p * 128))[tid];
        __syncthreads();

        {   // xw = A@Wp + bp, k-split x2
            const int kh = tid >> 8, unit = tid & 255, lr = unit >> 5, c4 = unit & 31;
            const float4* W4 = (const float4*)Wp;
            float4 acc = (kh == 0) ? ((const float4*)bp)[c4] : make_float4(0.f, 0.f, 0.f, 0.f);
            const int k0 = kh * 64;
            #pragma unroll 8
            for (int k = 0; k < 64; ++k) {
                const float a = Ash[lr * 128 + k0 + k];
                const float4 w = W4[(k0 + k) * 32 + c4];
                acc.x = fmaf(a, w.x, acc.x); acc.y = fmaf(a, w.y, acc.y);
                acc.z = fmaf(a, w.z, acc.z); acc.w = fmaf(a, w.w, acc.w);
            }
            ((float4*)Pp)[kh * 256 + unit] = acc;
        }
        __syncthreads();
        if (tid < 256) {
            const int lr = tid >> 5, c4 = tid & 31;
            const float4 a = ((const float4*)Pp)[tid];
            const float4 bq = ((const float4*)Pp)[256 + tid];
            const float4 w = make_float4(a.x + bq.x, a.y + bq.y, a.z + bq.z, a.w + bq.w);
            ((float4*)Pw)[tid] = w;
            ((float4*)o_w)[(size_t)(r0p + lr) * 32 + c4] = w;
        }
        __syncthreads();
        {   // {qa,kb} (or {kb2,ka2}) concurrently: which = tid>>8
            const int which = tid >> 8, unit = tid & 255, lr = unit >> 5, c4 = unit & 31;
            const float* W = which ? Wthr : Wsec;
            const float* bb = which ? nullptr : bsec;
            float* o = which ? o_t : o_s;
            const float4* W4 = (const float4*)W;
            float4 acc = bb ? ((const float4*)bb)[c4] : make_float4(0.f, 0.f, 0.f, 0.f);
            #pragma unroll 8
            for (int k = 0; k < 128; ++k) {
                const float a = Pw[lr * 128 + k];
                const float4 w = W4[k * 32 + c4];
                acc.x = fmaf(a, w.x, acc.x); acc.y = fmaf(a, w.y, acc.y);
                acc.z = fmaf(a, w.z, acc.z); acc.w = fmaf(a, w.w, acc.w);
            }
            ((float4*)o)[(size_t)(r0p + lr) * 32 + c4] = acc;
        }
    }

    // ---------- device-wide barrier (the ONLY one) ----------
    __threadfence();                 // release: drain + writeback
    __syncthreads();
    if (tid == 0) {
        __hip_atomic_fetch_add(p.ctr, 1u, __ATOMIC_ACQ_REL, __HIP_MEMORY_SCOPE_AGENT);
        while (__hip_atomic_load(p.ctr, __ATOMIC_ACQUIRE, __HIP_MEMORY_SCOPE_AGENT) < NBLK) {
            __builtin_amdgcn_s_sleep(2);
        }
    }
    __syncthreads();
    __threadfence();                 // acquire: invalidate stale lines

    // ---------- stages B/C: attn1(+qproj->LDS), attn2(+FFN) ----------
    const int r0 = bid * 4, bS = (r0 >> 8) * S;
    attn_stage<true >(p, smem, tid, r0, bS);
    attn_stage<false>(p, smem, tid, r0, bS);
}

extern "C" void kernel_launch(void* const* d_in, const int* in_sizes, int n_in,
                              void* d_out, int out_size, void* d_ws, size_t ws_size,
                              hipStream_t stream) {
    (void)in_sizes; (void)n_in; (void)out_size; (void)ws_size;
    P p;
    p.x        = (const float*)d_in[0];
    p.enc      = (const float*)d_in[1];
    p.com_mask = (const float*)d_in[2];
    p.dec_mask = (const float*)d_in[3];
    p.W1q = (const float*)d_in[4];
    p.W1k = (const float*)d_in[5];
    p.b1  = (const float*)d_in[6];
    p.W2  = (const float*)d_in[7];
    // d_in[8] = b2: per-row constant -> dropped (softmax shift invariance)
    p.Ww1 = (const float*)d_in[9];
    p.bw1 = (const float*)d_in[10];
    p.Wd1 = (const float*)d_in[11];
    p.bd1 = (const float*)d_in[12];
    p.Ww2 = (const float*)d_in[13];
    p.bw2 = (const float*)d_in[14];
    p.Wd2 = (const float*)d_in[15];
    p.bd2 = (const float*)d_in[16];
    p.Wf1 = (const float*)d_in[17];
    p.bf1 = (const float*)d_in[18];
    p.Wf2 = (const float*)d_in[19];
    p.bf2 = (const float*)d_in[20];
    p.ln1g = (const float*)d_in[21];
    p.ln1b = (const float*)d_in[22];
    p.ln2g = (const float*)d_in[23];
    p.ln2b = (const float*)d_in[24];
    p.ln3g = (const float*)d_in[25];
    p.ln3b = (const float*)d_in[26];
    p.out  = (float*)d_out;

    p.ctr = (unsigned int*)d_ws;
    float* ws = (float*)d_ws + 64;        // 256B offset past the counter
    const size_t RD = (size_t)R * D;      // 131072
    p.xw    = ws;
    p.qa    = p.xw    + RD;
    p.kb    = p.qa    + RD;
    p.kv2w  = p.kb    + RD;
    p.kb2   = p.kv2w  + RD;
    p.ka2   = p.kb2   + RD;

    // zero the barrier counter each graph replay (workspace is poisoned)
    hipMemsetAsync(d_ws, 0, 256, stream);
    mega_kernel<<<NBLK, 512, 0, stream>>>(p);
}

// Round 4
// 164.534 us; speedup vs baseline: 1.5316x; 1.5316x over previous
//
#include <hip/hip_runtime.h>
#include <math.h>

// DecoderLayer: B=4,N=1,S=256,D=128,H=128,DFF=512, fp32 end-to-end.
// Round-13: 2 dispatches, no device barrier, no fences, no LDS staging in
// scoring. R12 post-mortem: mega=162us @ VALUBusy 12%, HBM 1.7% ->
// latency/serialization-bound; in-kernel agent-scope threadfence wiped L2
// (FETCH 17.8MB) and cost +78us. R10/R11 showed kernel BOUNDARIES are cheap;
// the cost is INSIDE: barrier-serialized stage->sync->compute phases at
// 1 block/CU expose every latency.
//  1. proj3 (R11 form): x->xw->{qa,kb}; enc->kv2w->{kb2,ka2}
//  2. fused_attn12: attn1(+qproj->LDS) then attn2(+FFN) in one kernel --
//     chain is block-local (qa2/qb2/out1 live in LDS, proven R12).
//     Scoring reads streamed k-rows DIRECTLY from global L2 (16 independent
//     16B loads/tile/thread, deep MLP), zero ds_write, zero per-tile
//     barriers (8 fewer syncthreads per stage).
// Grid law (R6/R7): both kernels >= 256 blocks. b2 dropped (softmax shift
// invariance). RES_RATIO=1 -> plain residual add.

#define LN_EPS 1e-6f
#define NEGV  (-1e9f)

constexpr int B = 4, S = 256, D = 128, H = 128, DFF = 512;
constexpr int R = B * S;   // 1024 rows (N=1)

struct P {
    const float *x, *enc, *com_mask, *dec_mask;
    const float *W1q, *W1k, *b1, *W2;
    const float *Ww1, *bw1, *Wd1, *bd1;
    const float *Ww2, *bw2, *Wd2, *bd2;
    const float *Wf1, *bf1, *Wf2, *bf2;
    const float *ln1g, *ln1b, *ln2g, *ln2b, *ln3g, *ln3b;
    float *out;
    float *xw, *qa, *kb, *kv2w, *kb2, *ka2;
};

// ================= 1: chained projections, grid (R/8, 2), 512 thr =========
__global__ __launch_bounds__(512) void proj3_kernel(P p)
{
    const int g = blockIdx.y, tid = threadIdx.x;
    const int r0 = blockIdx.x * 8;
    __shared__ __align__(16) float Ash[8 * 128];
    __shared__ __align__(16) float Pw[8 * 128];
    __shared__ __align__(16) float Pp[2 * 8 * 128];  // k-split partials

    const float* A    = g ? p.enc  : p.x;
    const float* Wp   = g ? p.Ww2  : p.Ww1;
    const float* bp   = g ? p.bw2  : p.bw1;
    float*       o_w  = g ? p.kv2w : p.xw;
    const float* Wsec = g ? p.W1k  : p.W1q;  // kb2 | qa
    const float* bsec = g ? nullptr: p.b1;
    float*       o_s  = g ? p.kb2  : p.qa;
    const float* Wthr = g ? p.W1q  : p.W1k;  // ka2 | kb
    float*       o_t  = g ? p.ka2  : p.kb;

    if (tid < 256)
        ((float4*)Ash)[tid] = ((const float4*)(A + (size_t)r0 * 128))[tid];
    __syncthreads();

    // ---- xw = A@Wp + bp, k-split x2 (64-deep chains) ----
    {
        const int kh = tid >> 8, unit = tid & 255, lr = unit >> 5, c4 = unit & 31;
        const float4* W4 = (const float4*)Wp;
        float4 acc = (kh == 0) ? ((const float4*)bp)[c4] : make_float4(0.f, 0.f, 0.f, 0.f);
        const int k0 = kh * 64;
        #pragma unroll 8
        for (int k = 0; k < 64; ++k) {
            const float a = Ash[lr * 128 + k0 + k];
            const float4 w = W4[(k0 + k) * 32 + c4];
            acc.x = fmaf(a, w.x, acc.x); acc.y = fmaf(a, w.y, acc.y);
            acc.z = fmaf(a, w.z, acc.z); acc.w = fmaf(a, w.w, acc.w);
        }
        ((float4*)Pp)[kh * 256 + unit] = acc;
    }
    __syncthreads();
    if (tid < 256) {
        const int lr = tid >> 5, c4 = tid & 31;
        const float4 a = ((const float4*)Pp)[tid];
        const float4 bq = ((const float4*)Pp)[256 + tid];
        const float4 w = make_float4(a.x + bq.x, a.y + bq.y, a.z + bq.z, a.w + bq.w);
        ((float4*)Pw)[tid] = w;
        ((float4*)o_w)[(size_t)(r0 + lr) * 32 + c4] = w;
    }
    __syncthreads();

    // ---- {qa,kb} (or {kb2,ka2}) concurrently: which = tid>>8 ----
    {
        const int which = tid >> 8, unit = tid & 255, lr = unit >> 5, c4 = unit & 31;
        const float* W = which ? Wthr : Wsec;
        const float* bb = which ? nullptr : bsec;
        float* o = which ? o_t : o_s;
        const float4* W4 = (const float4*)W;
        float4 acc = bb ? ((const float4*)bb)[c4] : make_float4(0.f, 0.f, 0.f, 0.f);
        #pragma unroll 8
        for (int k = 0; k < 128; ++k) {
            const float a = Pw[lr * 128 + k];
            const float4 w = W4[k * 32 + c4];
            acc.x = fmaf(a, w.x, acc.x); acc.y = fmaf(a, w.y, acc.y);
            acc.z = fmaf(a, w.z, acc.z); acc.w = fmaf(a, w.w, acc.w);
        }
        ((float4*)o)[(size_t)(r0 + lr) * 32 + c4] = acc;
    }
}

// ---- scoring: 8 fma/fmax pairs (two relu-dot terms, 4 h-components) ----
#define SC8(ACC, O1, X1, O2, X2)                                               \
    ACC = fmaf(fmaxf((O1).x + (X1).x, 0.f), w.x, ACC);                         \
    ACC = fmaf(fmaxf((O1).y + (X1).y, 0.f), w.y, ACC);                         \
    ACC = fmaf(fmaxf((O1).z + (X1).z, 0.f), w.z, ACC);                         \
    ACC = fmaf(fmaxf((O1).w + (X1).w, 0.f), w.w, ACC);                         \
    ACC = fmaf(fmaxf((O2).x + (X2).x, 0.f), w.x, ACC);                         \
    ACC = fmaf(fmaxf((O2).y + (X2).y, 0.f), w.y, ACC);                         \
    ACC = fmaf(fmaxf((O2).z + (X2).z, 0.f), w.z, ACC);                         \
    ACC = fmaf(fmaxf((O2).w + (X2).w, 0.f), w.w, ACC);

// ====== fused attn stage: scoring + softmax + AV + outproj + LN + tail ======
// smem (floats): s8 [0,1024) | rowS [1024,1536) | scratch from 1536:
//   avp@1536(2048) aoS@3584(512) pp@4096(2048) qpp@6144(2048) q2wS@8192(512)
//   qp2@8704(2048) | FFN: hidP@1536(8192) part@9984(8192)
//   | qa2L@18432(512) qb2L@18944(512).
template<bool FIRST>
__device__ __forceinline__ void attn_stage(const P& p, float* smem,
                                           int tid, int r0, int bS)
{
    float* s8   = smem;          // [4][256] scores -> probs
    float* rowS = smem + 1024;   // [4][128] LN output (out1 survives here)
    float* qa2L = smem + 18432;  // [4][128]
    float* qb2L = smem + 18944;  // [4][128]

    const float* __restrict__ S1g = FIRST ? p.kb : p.kb2;   // streamed term1
    const float* __restrict__ S2g = FIRST ? p.qa : p.ka2;   // streamed term2
    const float* mask = FIRST ? p.com_mask : p.dec_mask;
    const float* V    = FIRST ? p.xw : p.kv2w;
    const float* Wd   = FIRST ? p.Wd1 : p.Wd2;
    const float* bd   = FIRST ? p.bd1 : p.bd2;
    const float* lg   = FIRST ? p.ln1g : p.ln2g;
    const float* lb   = FIRST ? p.ln1b : p.ln2b;

    // ---------------- scoring (direct-global streaming, no LDS staging) ----
    // s[r,k] = sum_h relu(O1[r,h]+S1[k,h])*W2[h] + relu(O2[r,h]+S2[k,h])*W2[h]
    // thread: hh = tid&7 (h-split, h = hh*4 + 32j), unit = tid>>3:
    //   kk = unit&31 (k-pair {kk, kk+32} within 64-row tile), rg = unit>>5.
    {
        const int hh = tid & 7, unit = tid >> 3, kk = unit & 31, rg = unit >> 5;
        const int rA = r0 + 2 * rg, rB = rA + 1;

        float4 o1A[4], o1B[4], o2A[4], o2B[4], w2r[4];
        #pragma unroll
        for (int j = 0; j < 4; ++j) {
            const int h = hh * 4 + 32 * j;
            if (FIRST) {
                o1A[j] = *(const float4*)(p.qa + (size_t)rA * H + h);
                o1B[j] = *(const float4*)(p.qa + (size_t)rB * H + h);
                o2A[j] = *(const float4*)(p.kb + (size_t)rA * H + h);
                o2B[j] = *(const float4*)(p.kb + (size_t)rB * H + h);
            } else {
                o1A[j] = *(const float4*)(qa2L + (2 * rg)     * H + h);
                o1B[j] = *(const float4*)(qa2L + (2 * rg + 1) * H + h);
                o2A[j] = *(const float4*)(qb2L + (2 * rg)     * H + h);
                o2B[j] = *(const float4*)(qb2L + (2 * rg + 1) * H + h);
            }
            w2r[j] = *(const float4*)(p.W2 + h);
        }

        for (int kt = 0; kt < 4; ++kt) {
            const float* __restrict__ r1a = S1g + (size_t)(bS + kt * 64 + kk)      * H;
            const float* __restrict__ r1b = S1g + (size_t)(bS + kt * 64 + kk + 32) * H;
            const float* __restrict__ r2a = S2g + (size_t)(bS + kt * 64 + kk)      * H;
            const float* __restrict__ r2b = S2g + (size_t)(bS + kt * 64 + kk + 32) * H;

            // 16 independent 16B loads (deep MLP), then compute
            float4 x1a[4], x1b[4], x2a[4], x2b[4];
            #pragma unroll
            for (int j = 0; j < 4; ++j) {
                const int h = hh * 4 + 32 * j;
                x1a[j] = *(const float4*)(r1a + h);
                x1b[j] = *(const float4*)(r1b + h);
                x2a[j] = *(const float4*)(r2a + h);
                x2b[j] = *(const float4*)(r2b + h);
            }

            float aAa = 0.f, aAb = 0.f, aBa = 0.f, aBb = 0.f;
            #pragma unroll
            for (int j = 0; j < 4; ++j) {
                const float4 w = w2r[j];
                SC8(aAa, o1A[j], x1a[j], o2A[j], x2a[j])
                SC8(aAb, o1A[j], x1b[j], o2A[j], x2b[j])
                SC8(aBa, o1B[j], x1a[j], o2B[j], x2a[j])
                SC8(aBb, o1B[j], x1b[j], o2B[j], x2b[j])
            }
            // h-reduce across the 8 hh lanes of this unit (width-8 shuffle)
            #pragma unroll
            for (int o = 1; o < 8; o <<= 1) {
                aAa += __shfl_xor(aAa, o, 8);
                aAb += __shfl_xor(aAb, o, 8);
                aBa += __shfl_xor(aBa, o, 8);
                aBb += __shfl_xor(aBb, o, 8);
            }
            if (hh == 0) {
                const int kb0 = kt * 64;
                s8[(2 * rg)     * 256 + kb0 + kk]      = aAa;
                s8[(2 * rg)     * 256 + kb0 + kk + 32] = aAb;
                s8[(2 * rg + 1) * 256 + kb0 + kk]      = aBa;
                s8[(2 * rg + 1) * 256 + kb0 + kk + 32] = aBb;
            }
        }
    }
    __syncthreads();

    // ---- mask add ----
    for (int i = tid; i < 1024; i += 512) {
        const int r = i >> 8, k = i & 255;
        s8[i] += mask[(size_t)(r0 + r) * S + k] * NEGV;
    }
    __syncthreads();

    // ---- softmax: waves 0-3 own rows 0-3; 64-lane shuffles ----
    {
        const int g = tid >> 6, c = tid & 63;
        if (g < 4) {
            float* rowp = s8 + g * 256;
            float m = -INFINITY;
            #pragma unroll
            for (int k = c; k < 256; k += 64) m = fmaxf(m, rowp[k]);
            for (int o = 32; o; o >>= 1) m = fmaxf(m, __shfl_xor(m, o, 64));
            float s = 0.f;
            #pragma unroll
            for (int k = c; k < 256; k += 64) { const float e = __expf(rowp[k] - m); rowp[k] = e; s += e; }
            for (int o = 32; o; o >>= 1) s += __shfl_xor(s, o, 64);
            const float rinv = 1.f / s;
            #pragma unroll
            for (int k = c; k < 256; k += 64) rowp[k] *= rinv;
        }
    }
    __syncthreads();

    float* avp = smem + 1536;   // [4][4][128] AV k-split partials
    float* aoS = smem + 3584;   // [4][128]
    float* pp  = smem + 4096;   // [4][4][128] outproj partials

    // ---- AV, k-split x4: row r, quarter kq ----
    {
        const int r = tid >> 7, t = tid & 127, kq = t >> 5, c4 = t & 31;
        const float4* V4 = (const float4*)(V + (size_t)bS * D);
        const float* sp = s8 + r * 256 + kq * 64;
        float4 acc = make_float4(0.f, 0.f, 0.f, 0.f);
        #pragma unroll 8
        for (int k = 0; k < 64; ++k) {
            const float a = sp[k];
            const float4 v = V4[(kq * 64 + k) * 32 + c4];
            acc.x = fmaf(a, v.x, acc.x); acc.y = fmaf(a, v.y, acc.y);
            acc.z = fmaf(a, v.z, acc.z); acc.w = fmaf(a, v.w, acc.w);
        }
        ((float4*)avp)[(r * 4 + kq) * 32 + c4] = acc;
    }
    __syncthreads();
    if (tid < 128) {
        const int r = tid >> 5, c4 = tid & 31;
        float4 s0 = ((const float4*)avp)[(r * 4 + 0) * 32 + c4];
        const float4 s1 = ((const float4*)avp)[(r * 4 + 1) * 32 + c4];
        const float4 s2 = ((const float4*)avp)[(r * 4 + 2) * 32 + c4];
        const float4 s3 = ((const float4*)avp)[(r * 4 + 3) * 32 + c4];
        s0.x += s1.x + s2.x + s3.x; s0.y += s1.y + s2.y + s3.y;
        s0.z += s1.z + s2.z + s3.z; s0.w += s1.w + s2.w + s3.w;
        ((float4*)aoS)[r * 32 + c4] = s0;
    }
    __syncthreads();

    // ---- outproj, k-split x4 ----
    {
        const int kq = tid >> 7, unit = tid & 127, r = unit >> 5, c4 = unit & 31;
        const float4* W4 = (const float4*)Wd;
        const float* ap = aoS + r * 128 + kq * 32;
        float4 acc = make_float4(0.f, 0.f, 0.f, 0.f);
        #pragma unroll 8
        for (int k = 0; k < 32; ++k) {
            const float a = ap[k];
            const float4 w = W4[(kq * 32 + k) * 32 + c4];
            acc.x = fmaf(a, w.x, acc.x); acc.y = fmaf(a, w.y, acc.y);
            acc.z = fmaf(a, w.z, acc.z); acc.w = fmaf(a, w.w, acc.w);
        }
        ((float4*)pp)[kq * 128 + unit] = acc;
    }
    __syncthreads();

    // ---- combine + bias + residual + LN -> rowS ----
    if (tid < 128) {
        const int r = tid >> 5, c4 = tid & 31;
        const float4 p0 = ((const float4*)pp)[tid];
        const float4 p1 = ((const float4*)pp)[128 + tid];
        const float4 p2 = ((const float4*)pp)[256 + tid];
        const float4 p3 = ((const float4*)pp)[384 + tid];
        const float4 bv0 = ((const float4*)bd)[c4];
        float4 r4;
        if (FIRST) r4 = ((const float4*)(p.x + (size_t)(r0 + r) * 128))[c4];
        else       r4 = ((const float4*)rowS)[r * 32 + c4];
        const float x0 = p0.x + p1.x + p2.x + p3.x + bv0.x + r4.x;
        const float x1 = p0.y + p1.y + p2.y + p3.y + bv0.y + r4.y;
        const float x2 = p0.z + p1.z + p2.z + p3.z + bv0.z + r4.z;
        const float x3 = p0.w + p1.w + p2.w + p3.w + bv0.w + r4.w;
        float s  = x0 + x1 + x2 + x3;
        float s2 = x0 * x0 + x1 * x1 + x2 * x2 + x3 * x3;
        for (int o = 16; o; o >>= 1) { s += __shfl_xor(s, o, 32); s2 += __shfl_xor(s2, o, 32); }
        const float m = s * (1.f / 128), var = s2 * (1.f / 128) - m * m;
        const float rs = rsqrtf(var + LN_EPS);
        const float4 gv = ((const float4*)lg)[c4], bv = ((const float4*)lb)[c4];
        float4 o4;
        o4.x = (x0 - m) * rs * gv.x + bv.x; o4.y = (x1 - m) * rs * gv.y + bv.y;
        o4.z = (x2 - m) * rs * gv.z + bv.z; o4.w = (x3 - m) * rs * gv.w + bv.w;
        ((float4*)rowS)[r * 32 + c4] = o4;
    }
    __syncthreads();

    if (FIRST) {
        // ---- qproj: q2w = LN1out@Ww2+bw2; qa2/qb2 = q2w@{W1q,W1k}+b1 -> LDS
        float* qpp  = smem + 6144;  // [4][4][32] f4 partials (2048 floats)
        float* q2wS = smem + 8192;  // [4][128]
        float* qp2  = smem + 8704;  // [2][2][128] f4 partials (2048 floats)
        {   // q2w partials, k-split x4
            const int kq = tid >> 7, unit = tid & 127, r = unit >> 5, c4 = unit & 31;
            const float4* W4 = (const float4*)p.Ww2;
            const float* ap = rowS + r * 128 + kq * 32;
            float4 acc = make_float4(0.f, 0.f, 0.f, 0.f);
            #pragma unroll 8
            for (int k = 0; k < 32; ++k) {
                const float a = ap[k];
                const float4 w = W4[(kq * 32 + k) * 32 + c4];
                acc.x = fmaf(a, w.x, acc.x); acc.y = fmaf(a, w.y, acc.y);
                acc.z = fmaf(a, w.z, acc.z); acc.w = fmaf(a, w.w, acc.w);
            }
            ((float4*)qpp)[kq * 128 + unit] = acc;
        }
        __syncthreads();
        if (tid < 128) {
            const int c4 = tid & 31;
            const float4 p0 = ((const float4*)qpp)[tid];
            const float4 p1 = ((const float4*)qpp)[128 + tid];
            const float4 p2 = ((const float4*)qpp)[256 + tid];
            const float4 p3 = ((const float4*)qpp)[384 + tid];
            const float4 bw = ((const float4*)p.bw2)[c4];
            ((float4*)q2wS)[tid] = make_float4(p0.x + p1.x + p2.x + p3.x + bw.x,
                                               p0.y + p1.y + p2.y + p3.y + bw.y,
                                               p0.z + p1.z + p2.z + p3.z + bw.z,
                                               p0.w + p1.w + p2.w + p3.w + bw.w);
        }
        __syncthreads();
        {   // qa2 = q2w@W1q + b1 ; qb2 = q2w@W1k + b1 ; k-split x2
            const int which = tid >> 8, sub = tid & 255;
            const int kh = sub >> 7, unit2 = sub & 127;
            const float4* W4 = (const float4*)(which ? p.W1k : p.W1q);
            const int r = unit2 >> 5;
            const float* ap = q2wS + r * 128 + kh * 64;
            float4 acc = make_float4(0.f, 0.f, 0.f, 0.f);
            #pragma unroll 8
            for (int k = 0; k < 64; ++k) {
                const float a = ap[k];
                const float4 w = W4[(kh * 64 + k) * 32 + (unit2 & 31)];
                acc.x = fmaf(a, w.x, acc.x); acc.y = fmaf(a, w.y, acc.y);
                acc.z = fmaf(a, w.z, acc.z); acc.w = fmaf(a, w.w, acc.w);
            }
            ((float4*)qp2)[(which * 2 + kh) * 128 + unit2] = acc;
        }
        __syncthreads();
        if (tid < 256) {   // reduce 2 k-halves + b1 -> qa2L/qb2L (LDS only)
            const int which = tid >> 7, unit2 = tid & 127;
            const int c4 = unit2 & 31;
            const float4 p0 = ((const float4*)qp2)[(which * 2 + 0) * 128 + unit2];
            const float4 p1 = ((const float4*)qp2)[(which * 2 + 1) * 128 + unit2];
            const float4 b1v = ((const float4*)p.b1)[c4];
            float* oq = which ? qb2L : qa2L;
            ((float4*)oq)[unit2] =
                make_float4(p0.x + p1.x + b1v.x, p0.y + p1.y + b1v.y,
                            p0.z + p1.z + b1v.z, p0.w + p1.w + b1v.w);
        }
        __syncthreads();
    } else {
        // ---- FFN + LN3 -> out ----
        float* hidP = smem + 1536;  // [4 kh][4 r][512] partials; [0,2048) -> hidden
        float* part = smem + 9984;  // [16 kg][4 r][128]
        {   // ffn1: float4-col c of 128 (DFF/4), k-quarter kh; 4-row reg accs
            const int c = tid & 127, kh = tid >> 7;
            const float4* Wf1_4 = (const float4*)p.Wf1;
            float4 a0 = make_float4(0.f,0.f,0.f,0.f), a1 = a0, a2 = a0, a3 = a0;
            const int kbase = kh * 32;
            #pragma unroll 8
            for (int k = 0; k < 32; ++k) {
                const int kk = kbase + k;
                const float4 w = Wf1_4[kk * 128 + c];
                const float s0 = rowS[kk],       s1 = rowS[128 + kk];
                const float s2 = rowS[256 + kk], s3 = rowS[384 + kk];
                a0.x=fmaf(s0,w.x,a0.x); a0.y=fmaf(s0,w.y,a0.y); a0.z=fmaf(s0,w.z,a0.z); a0.w=fmaf(s0,w.w,a0.w);
                a1.x=fmaf(s1,w.x,a1.x); a1.y=fmaf(s1,w.y,a1.y); a1.z=fmaf(s1,w.z,a1.z); a1.w=fmaf(s1,w.w,a1.w);
                a2.x=fmaf(s2,w.x,a2.x); a2.y=fmaf(s2,w.y,a2.y); a2.z=fmaf(s2,w.z,a2.z); a2.w=fmaf(s2,w.w,a2.w);
                a3.x=fmaf(s3,w.x,a3.x); a3.y=fmaf(s3,w.y,a3.y); a3.z=fmaf(s3,w.z,a3.z); a3.w=fmaf(s3,w.w,a3.w);
            }
            float4* h4 = (float4*)hidP;
            const int base = kh * 512;
            h4[base + 0*128 + c] = a0; h4[base + 1*128 + c] = a1;
            h4[base + 2*128 + c] = a2; h4[base + 3*128 + c] = a3;
        }
        __syncthreads();
        for (int i = tid; i < 2048; i += 512) {   // reduce 4 k-quarters + relu
            hidP[i] = fmaxf(hidP[i] + hidP[2048 + i] + hidP[4096 + i] + hidP[6144 + i]
                            + p.bf1[i & 511], 0.f);
        }
        __syncthreads();
        {   // ffn2: c4f of 32, k-group kg (16 x 32); 4-row reg accs
            const int c4f = tid & 31, kg = tid >> 5;
            const float4* Wf2_4 = (const float4*)p.Wf2;
            float4 a0 = make_float4(0.f,0.f,0.f,0.f), a1 = a0, a2 = a0, a3 = a0;
            const int kbase = kg * 32;
            const float* h0 = hidP + 0 * 512 + kbase;
            const float* h1 = hidP + 1 * 512 + kbase;
            const float* h2 = hidP + 2 * 512 + kbase;
            const float* h3 = hidP + 3 * 512 + kbase;
            #pragma unroll 8
            for (int k = 0; k < 32; ++k) {
                const float4 w = Wf2_4[(kbase + k) * 32 + c4f];
                const float s0 = h0[k], s1 = h1[k], s2 = h2[k], s3 = h3[k];
                a0.x=fmaf(s0,w.x,a0.x); a0.y=fmaf(s0,w.y,a0.y); a0.z=fmaf(s0,w.z,a0.z); a0.w=fmaf(s0,w.w,a0.w);
                a1.x=fmaf(s1,w.x,a1.x); a1.y=fmaf(s1,w.y,a1.y); a1.z=fmaf(s1,w.z,a1.z); a1.w=fmaf(s1,w.w,a1.w);
                a2.x=fmaf(s2,w.x,a2.x); a2.y=fmaf(s2,w.y,a2.y); a2.z=fmaf(s2,w.z,a2.z); a2.w=fmaf(s2,w.w,a2.w);
                a3.x=fmaf(s3,w.x,a3.x); a3.y=fmaf(s3,w.y,a3.y); a3.z=fmaf(s3,w.z,a3.z); a3.w=fmaf(s3,w.w,a3.w);
            }
            float4* p4 = (float4*)part;
            p4[kg * 128 + 0 * 32 + c4f] = a0; p4[kg * 128 + 1 * 32 + c4f] = a1;
            p4[kg * 128 + 2 * 32 + c4f] = a2; p4[kg * 128 + 3 * 32 + c4f] = a3;
        }
        __syncthreads();
        if (tid < 128) {  // reduce 16 k-partials + bias + residual + LN3 -> out
            const int r = tid >> 5, c4 = tid & 31;
            const float4* p4 = (const float4*)part;
            float4 sum = ((const float4*)p.bf2)[c4];
            #pragma unroll
            for (int kg = 0; kg < 16; ++kg) {
                const float4 v = p4[kg * 128 + r * 32 + c4];
                sum.x += v.x; sum.y += v.y; sum.z += v.z; sum.w += v.w;
            }
            const float4 r4 = ((const float4*)rowS)[r * 32 + c4];
            const float x0 = sum.x + r4.x, x1 = sum.y + r4.y;
            const float x2 = sum.z + r4.z, x3 = sum.w + r4.w;
            float s  = x0 + x1 + x2 + x3;
            float s2 = x0 * x0 + x1 * x1 + x2 * x2 + x3 * x3;
            for (int o = 16; o; o >>= 1) { s += __shfl_xor(s, o, 32); s2 += __shfl_xor(s2, o, 32); }
            const float m = s * (1.f / 128), var = s2 * (1.f / 128) - m * m;
            const float rs = rsqrtf(var + LN_EPS);
            const float4 gv = ((const float4*)p.ln3g)[c4], bv = ((const float4*)p.ln3b)[c4];
            float4 o4;
            o4.x = (x0 - m) * rs * gv.x + bv.x; o4.y = (x1 - m) * rs * gv.y + bv.y;
            o4.z = (x2 - m) * rs * gv.z + bv.z; o4.w = (x3 - m) * rs * gv.w + bv.w;
            ((float4*)p.out)[(size_t)(r0 + r) * 32 + c4] = o4;
        }
    }
}

// ================= 2: fused attn1 + attn2, grid R/4 = 256 ==================
__global__ __launch_bounds__(512) void fused_attn12_kernel(P p)
{
    __shared__ __align__(16) float smem[19456];
    const int tid = threadIdx.x;
    const int r0 = blockIdx.x * 4, bS = (r0 >> 8) * S;
    attn_stage<true >(p, smem, tid, r0, bS);
    attn_stage<false>(p, smem, tid, r0, bS);
}

extern "C" void kernel_launch(void* const* d_in, const int* in_sizes, int n_in,
                              void* d_out, int out_size, void* d_ws, size_t ws_size,
                              hipStream_t stream) {
    (void)in_sizes; (void)n_in; (void)out_size; (void)ws_size;
    P p;
    p.x        = (const float*)d_in[0];
    p.enc      = (const float*)d_in[1];
    p.com_mask = (const float*)d_in[2];
    p.dec_mask = (const float*)d_in[3];
    p.W1q = (const float*)d_in[4];
    p.W1k = (const float*)d_in[5];
    p.b1  = (const float*)d_in[6];
    p.W2  = (const float*)d_in[7];
    // d_in[8] = b2: per-row constant -> dropped (softmax shift invariance)
    p.Ww1 = (const float*)d_in[9];
    p.bw1 = (const float*)d_in[10];
    p.Wd1 = (const float*)d_in[11];
    p.bd1 = (const float*)d_in[12];
    p.Ww2 = (const float*)d_in[13];
    p.bw2 = (const float*)d_in[14];
    p.Wd2 = (const float*)d_in[15];
    p.bd2 = (const float*)d_in[16];
    p.Wf1 = (const float*)d_in[17];
    p.bf1 = (const float*)d_in[18];
    p.Wf2 = (const float*)d_in[19];
    p.bf2 = (const float*)d_in[20];
    p.ln1g = (const float*)d_in[21];
    p.ln1b = (const float*)d_in[22];
    p.ln2g = (const float*)d_in[23];
    p.ln2b = (const float*)d_in[24];
    p.ln3g = (const float*)d_in[25];
    p.ln3b = (const float*)d_in[26];
    p.out  = (float*)d_out;

    float* ws = (float*)d_ws;
    const size_t RD = (size_t)R * D;      // 131072
    p.xw    = ws;
    p.qa    = p.xw    + RD;
    p.kb    = p.qa    + RD;
    p.kv2w  = p.kb    + RD;
    p.kb2   = p.kv2w  + RD;
    p.ka2   = p.kb2   + RD;

    proj3_kernel<<<dim3(R / 8, 2), 512, 0, stream>>>(p);
    fused_attn12_kernel<<<R / 4, 512, 0, stream>>>(p);
}